// Round 1
// baseline (131.306 us; speedup 1.0000x reference)
//
#include <hip/hip_runtime.h>

// ROI Align (FPN, levels 3..6), matching the reference's transposed sampling:
//   row coordinate = lX + (i + (s1+0.5)/2) * (max(rX-lX,1)/7)
//   col coordinate = tY + (j + (s2+0.5)/2) * (max(bY-tY,1)/7)
// out[n,c,i,j] = mean over (s1,s2) of bilinear samples (invalid -> 0, /4 always)

__global__ __launch_bounds__(256) void roi_align_kernel(
    const float* __restrict__ f3, const float* __restrict__ f4,
    const float* __restrict__ f5, const float* __restrict__ f6,
    const float* __restrict__ boxes, const int* __restrict__ img_ids,
    float* __restrict__ out)
{
    const int n  = blockIdx.x;       // ROI id
    const int cg = blockIdx.y;       // channel group (64 channels each)
    const int t  = threadIdx.x;      // 0..255

    // ---- box -> level ----
    const float by = boxes[n * 4 + 0];
    const float bx = boxes[n * 4 + 1];
    const float bh = boxes[n * 4 + 2];
    const float bw = boxes[n * 4 + 3];

    const float area = bh * bw;
    float kf = floorf(4.0f + log2f(sqrtf(area) / 224.0f));
    kf = fminf(fmaxf(kf, 3.0f), 6.0f);
    const int lvl = (int)kf;

    const float* feat;
    int H;
    if      (lvl == 3) { feat = f3; H = 128; }
    else if (lvl == 4) { feat = f4; H = 64;  }
    else if (lvl == 5) { feat = f5; H = 32;  }
    else               { feat = f6; H = 16;  }

    const float inv_stride = 1.0f / (float)(1 << lvl);  // exact (pow2)

    // tlbr / stride  (t=y-h/2, l=x-w/2, b=y+h/2, r=x+w/2)
    const float tY = (by - bh * 0.5f) * inv_stride;
    const float lX = (bx - bw * 0.5f) * inv_stride;
    const float bY = (by + bh * 0.5f) * inv_stride;
    const float rX = (bx + bw * 0.5f) * inv_stride;

    // reference's swapped naming: "roi_w"=b-t (rows span uses l..r!), see header
    const float roiA = fmaxf(bY - tY, 1.0f);   // "roi_w" -> col direction bins
    const float roiB = fmaxf(rX - lX, 1.0f);   // "roi_h" -> row direction bins
    const float binA = roiA / 7.0f;
    const float binB = roiB / 7.0f;

    // ---- per-thread sample ----
    // sid = p*4 + s1*2 + s2 ; p = i*7 + j ; lanes [196,256) idle
    const int sid = t;
    const int p   = sid >> 2;
    const int s1  = (sid >> 1) & 1;
    const int s2  = sid & 1;
    const int ii  = p / 7;
    const int jj  = p % 7;
    const bool active = (sid < 196);

    const float offR = (float)ii + ((float)s1 + 0.5f) * 0.5f;
    const float offC = (float)jj + ((float)s2 + 0.5f) * 0.5f;
    const float rc = lX + offR * binB;   // feature ROW coordinate
    const float cc = tY + offC * binA;   // feature COL coordinate

    const float Hf = (float)H;
    const bool valid = active &&
                       (rc >= -1.0f) && (rc <= Hf) &&
                       (cc >= -1.0f) && (cc <= Hf);

    const float yc = fminf(fmaxf(rc, 0.0f), Hf - 1.0f);
    const float xc = fminf(fmaxf(cc, 0.0f), Hf - 1.0f);
    int yl = (int)floorf(yc);
    int xl = (int)floorf(xc);
    int yh = min(yl + 1, H - 1);
    int xh = min(xl + 1, H - 1);
    const float ly = yc - (float)yl;
    const float lx = xc - (float)xl;
    const float hy = 1.0f - ly;
    const float hx = 1.0f - lx;
    float w00 = hy * hx, w01 = hy * lx, w10 = ly * hx, w11 = ly * lx;
    if (!valid) {
        w00 = w01 = w10 = w11 = 0.0f;
        yl = xl = yh = xh = 0;
    }

    const int img = img_ids[n];
    const int HH  = H * H;
    const int c0  = cg * 64;
    const float* base = feat + (size_t)(img * 256 + c0) * (size_t)HH;
    const int o00 = yl * H + xl;
    const int o01 = yl * H + xh;
    const int o10 = yh * H + xl;
    const int o11 = yh * H + xh;

    float* outp = out + ((size_t)n * 256 + c0) * 49 + p;

    #pragma unroll 4
    for (int c = 0; c < 64; ++c) {
        float v = w00 * base[o00] + w01 * base[o01]
                + w10 * base[o10] + w11 * base[o11];
        v += __shfl_xor(v, 1);
        v += __shfl_xor(v, 2);
        if (active && (t & 3) == 0) {
            outp[(size_t)c * 49] = v * 0.25f;
        }
        base += HH;
    }
}

extern "C" void kernel_launch(void* const* d_in, const int* in_sizes, int n_in,
                              void* d_out, int out_size, void* d_ws, size_t ws_size,
                              hipStream_t stream)
{
    const float* f3      = (const float*)d_in[0];
    const float* f4      = (const float*)d_in[1];
    const float* f5      = (const float*)d_in[2];
    const float* f6      = (const float*)d_in[3];
    const float* boxes   = (const float*)d_in[4];
    const int*   img_ids = (const int*)d_in[5];
    float* outp          = (float*)d_out;

    const int N = in_sizes[5];          // 1024 ROIs
    dim3 grid(N, 4);                    // (roi, 64-channel group)
    roi_align_kernel<<<grid, 256, 0, stream>>>(f3, f4, f5, f6, boxes, img_ids, outp);
}

// Round 2
// 88.573 us; speedup vs baseline: 1.4825x; 1.4825x over previous
//
#include <hip/hip_runtime.h>

// ws layout (floats): NHWC copies of the 4 feature levels
static constexpr size_t B3 = 0;
static constexpr size_t B4 = (size_t)4 * 256 * 16384;                 // after f3
static constexpr size_t B5 = B4 + (size_t)4 * 256 * 4096;             // after f4
static constexpr size_t B6 = B5 + (size_t)4 * 256 * 1024;             // after f5
static constexpr size_t WS_FLOATS = B6 + (size_t)4 * 256 * 256;       // 22,282,240

// ---------------- NCHW -> NHWC transpose (all levels, all images) ----------
__global__ __launch_bounds__(256) void transpose_nchw_nhwc(
    const float* __restrict__ f3, const float* __restrict__ f4,
    const float* __restrict__ f5, const float* __restrict__ f6,
    float* __restrict__ ws)
{
    __shared__ float tile[64][65];
    const int z   = blockIdx.z;         // lvl*4 + b
    const int lvl = z >> 2;
    const int b   = z & 3;
    const float* in; int H; size_t base;
    if      (lvl == 0) { in = f3; H = 128; base = B3; }
    else if (lvl == 1) { in = f4; H = 64;  base = B4; }
    else if (lvl == 2) { in = f5; H = 32;  base = B5; }
    else               { in = f6; H = 16;  base = B6; }
    const int HW  = H * H;
    const int hw0 = blockIdx.x * 64;
    if (hw0 >= HW) return;
    const int c0  = blockIdx.y * 64;
    const int tx  = threadIdx.x & 63;
    const int ty  = threadIdx.x >> 6;

    const float* inp = in + ((size_t)b * 256 + c0) * (size_t)HW + hw0;
    #pragma unroll
    for (int i = 0; i < 16; ++i) {
        const int cl = ty + 4 * i;
        tile[cl][tx] = inp[(size_t)cl * HW + tx];      // coalesced along hw
    }
    __syncthreads();
    float* outp = ws + base + ((size_t)b * HW + hw0) * 256 + c0;
    #pragma unroll
    for (int i = 0; i < 16; ++i) {
        const int hl = ty + 4 * i;
        outp[(size_t)hl * 256 + tx] = tile[tx][hl];    // coalesced along c
    }
}

// ---------------- ROI gather from NHWC -------------------------------------
__global__ __launch_bounds__(256) void roi_gather_nhwc(
    const float* __restrict__ ws, const float* __restrict__ boxes,
    const int* __restrict__ img_ids, float* __restrict__ out)
{
    __shared__ float lds[49][129];      // [bin][channel] staging, pad->conflict-free
    const int n    = blockIdx.x;        // ROI
    const int c0   = blockIdx.y * 128;  // channel half
    const int t    = threadIdx.x;
    const int lane = t & 63;
    const int wv   = t >> 6;            // 0..3

    const float by = boxes[n * 4 + 0];
    const float bx = boxes[n * 4 + 1];
    const float bh = boxes[n * 4 + 2];
    const float bw = boxes[n * 4 + 3];

    float kf = floorf(4.0f + log2f(sqrtf(bh * bw) / 224.0f));
    kf = fminf(fmaxf(kf, 3.0f), 6.0f);
    const int lvl = (int)kf;

    int H; size_t base;
    if      (lvl == 3) { H = 128; base = B3; }
    else if (lvl == 4) { H = 64;  base = B4; }
    else if (lvl == 5) { H = 32;  base = B5; }
    else               { H = 16;  base = B6; }
    const float inv_stride = 1.0f / (float)(1 << lvl);
    const float Hf = (float)H;

    // tlbr/stride with the reference's swapped axis semantics (round-1 verified)
    const float tY = (by - bh * 0.5f) * inv_stride;
    const float lX = (bx - bw * 0.5f) * inv_stride;
    const float bY = (by + bh * 0.5f) * inv_stride;
    const float rX = (bx + bw * 0.5f) * inv_stride;
    const float binA = fmaxf(bY - tY, 1.0f) * (1.0f / 7.0f);  // col direction
    const float binB = fmaxf(rX - lX, 1.0f) * (1.0f / 7.0f);  // row direction

    const int img = img_ids[n];
    const float* fb = ws + base + (size_t)img * (size_t)(H * H) * 256
                    + (size_t)c0 + 2 * lane;

    for (int p = wv; p < 49; p += 4) {
        const int ii = p / 7, jj = p % 7;
        float accx = 0.0f, accy = 0.0f;
        #pragma unroll
        for (int s = 0; s < 4; ++s) {
            const int s1 = s >> 1, s2 = s & 1;
            const float rc = lX + ((float)ii + ((float)s1 + 0.5f) * 0.5f) * binB;
            const float cc = tY + ((float)jj + ((float)s2 + 0.5f) * 0.5f) * binA;
            const bool valid = (rc >= -1.0f) && (rc <= Hf) &&
                               (cc >= -1.0f) && (cc <= Hf);
            const float yc = fminf(fmaxf(rc, 0.0f), Hf - 1.0f);
            const float xc = fminf(fmaxf(cc, 0.0f), Hf - 1.0f);
            const int yl = (int)yc;                 // yc >= 0: trunc == floor
            const int xl = (int)xc;
            const int yh = min(yl + 1, H - 1);
            const int xh = min(xl + 1, H - 1);
            const float ly = yc - (float)yl, lx2 = xc - (float)xl;
            const float hy = 1.0f - ly, hx = 1.0f - lx2;
            float w00 = hy * hx, w01 = hy * lx2, w10 = ly * hx, w11 = ly * lx2;
            if (!valid) { w00 = w01 = w10 = w11 = 0.0f; }

            const float2 v00 = *(const float2*)(fb + (size_t)(yl * H + xl) * 256);
            const float2 v01 = *(const float2*)(fb + (size_t)(yl * H + xh) * 256);
            const float2 v10 = *(const float2*)(fb + (size_t)(yh * H + xl) * 256);
            const float2 v11 = *(const float2*)(fb + (size_t)(yh * H + xh) * 256);
            accx += w00 * v00.x + w01 * v01.x + w10 * v10.x + w11 * v11.x;
            accy += w00 * v00.y + w01 * v01.y + w10 * v10.y + w11 * v11.y;
        }
        lds[p][2 * lane]     = accx * 0.25f;
        lds[p][2 * lane + 1] = accy * 0.25f;
    }
    __syncthreads();

    // coalesced NCHW write-out: lanes = bins, loop channels
    float* op = out + ((size_t)n * 256 + c0 + wv * 32) * 49;
    if (lane < 49) {
        for (int k = 0; k < 32; ++k) {
            op[(size_t)k * 49 + lane] = lds[lane][wv * 32 + k];
        }
    }
}

// ---------------- fallback (round-1, direct NCHW gather) -------------------
__global__ __launch_bounds__(256) void roi_align_fallback(
    const float* __restrict__ f3, const float* __restrict__ f4,
    const float* __restrict__ f5, const float* __restrict__ f6,
    const float* __restrict__ boxes, const int* __restrict__ img_ids,
    float* __restrict__ out)
{
    const int n  = blockIdx.x;
    const int cg = blockIdx.y;
    const int t  = threadIdx.x;

    const float by = boxes[n * 4 + 0];
    const float bx = boxes[n * 4 + 1];
    const float bh = boxes[n * 4 + 2];
    const float bw = boxes[n * 4 + 3];

    float kf = floorf(4.0f + log2f(sqrtf(bh * bw) / 224.0f));
    kf = fminf(fmaxf(kf, 3.0f), 6.0f);
    const int lvl = (int)kf;

    const float* feat;
    int H;
    if      (lvl == 3) { feat = f3; H = 128; }
    else if (lvl == 4) { feat = f4; H = 64;  }
    else if (lvl == 5) { feat = f5; H = 32;  }
    else               { feat = f6; H = 16;  }

    const float inv_stride = 1.0f / (float)(1 << lvl);
    const float tY = (by - bh * 0.5f) * inv_stride;
    const float lX = (bx - bw * 0.5f) * inv_stride;
    const float bY = (by + bh * 0.5f) * inv_stride;
    const float rX = (bx + bw * 0.5f) * inv_stride;
    const float binA = fmaxf(bY - tY, 1.0f) / 7.0f;
    const float binB = fmaxf(rX - lX, 1.0f) / 7.0f;

    const int sid = t;
    const int p   = sid >> 2;
    const int s1  = (sid >> 1) & 1;
    const int s2  = sid & 1;
    const int ii  = p / 7;
    const int jj  = p % 7;
    const bool active = (sid < 196);

    const float rc = lX + ((float)ii + ((float)s1 + 0.5f) * 0.5f) * binB;
    const float cc = tY + ((float)jj + ((float)s2 + 0.5f) * 0.5f) * binA;
    const float Hf = (float)H;
    const bool valid = active && (rc >= -1.0f) && (rc <= Hf) &&
                       (cc >= -1.0f) && (cc <= Hf);

    const float yc = fminf(fmaxf(rc, 0.0f), Hf - 1.0f);
    const float xc = fminf(fmaxf(cc, 0.0f), Hf - 1.0f);
    int yl = (int)floorf(yc);
    int xl = (int)floorf(xc);
    int yh = min(yl + 1, H - 1);
    int xh = min(xl + 1, H - 1);
    const float ly = yc - (float)yl;
    const float lx = xc - (float)xl;
    const float hy = 1.0f - ly;
    const float hx = 1.0f - lx;
    float w00 = hy * hx, w01 = hy * lx, w10 = ly * hx, w11 = ly * lx;
    if (!valid) { w00 = w01 = w10 = w11 = 0.0f; yl = xl = yh = xh = 0; }

    const int img = img_ids[n];
    const int HH  = H * H;
    const int c0  = cg * 64;
    const float* base = feat + (size_t)(img * 256 + c0) * (size_t)HH;
    const int o00 = yl * H + xl, o01 = yl * H + xh;
    const int o10 = yh * H + xl, o11 = yh * H + xh;

    float* outp = out + ((size_t)n * 256 + c0) * 49 + p;
    #pragma unroll 4
    for (int c = 0; c < 64; ++c) {
        float v = w00 * base[o00] + w01 * base[o01]
                + w10 * base[o10] + w11 * base[o11];
        v += __shfl_xor(v, 1);
        v += __shfl_xor(v, 2);
        if (active && (t & 3) == 0) outp[(size_t)c * 49] = v * 0.25f;
        base += HH;
    }
}

extern "C" void kernel_launch(void* const* d_in, const int* in_sizes, int n_in,
                              void* d_out, int out_size, void* d_ws, size_t ws_size,
                              hipStream_t stream)
{
    const float* f3      = (const float*)d_in[0];
    const float* f4      = (const float*)d_in[1];
    const float* f5      = (const float*)d_in[2];
    const float* f6      = (const float*)d_in[3];
    const float* boxes   = (const float*)d_in[4];
    const int*   img_ids = (const int*)d_in[5];
    float* outp          = (float*)d_out;
    const int N = in_sizes[5];                    // 1024 ROIs

    if (ws_size >= WS_FLOATS * sizeof(float)) {
        float* ws = (float*)d_ws;
        dim3 tgrid(256, 4, 16);                   // (hw tiles max, c tiles, lvl*4+b)
        transpose_nchw_nhwc<<<tgrid, 256, 0, stream>>>(f3, f4, f5, f6, ws);
        dim3 ggrid(N, 2);                         // (roi, channel half)
        roi_gather_nhwc<<<ggrid, 256, 0, stream>>>(ws, boxes, img_ids, outp);
    } else {
        dim3 grid(N, 4);
        roi_align_fallback<<<grid, 256, 0, stream>>>(f3, f4, f5, f6, boxes, img_ids, outp);
    }
}

// Round 3
// 57.784 us; speedup vs baseline: 2.2723x; 1.5328x over previous
//
#include <hip/hip_runtime.h>
#include <hip/hip_bf16.h>

// ws layout: bf16 NHWC copies of the 4 feature levels (element offsets)
static constexpr size_t B3 = 0;
static constexpr size_t B4 = (size_t)4 * 256 * 16384;                 // after f3
static constexpr size_t B5 = B4 + (size_t)4 * 256 * 4096;             // after f4
static constexpr size_t B6 = B5 + (size_t)4 * 256 * 1024;             // after f5
static constexpr size_t WS_ELEMS = B6 + (size_t)4 * 256 * 256;        // bf16 elems

// ---------------- NCHW fp32 -> NHWC bf16 transpose -------------------------
__global__ __launch_bounds__(256) void transpose_nchw_nhwc_bf16(
    const float* __restrict__ f3, const float* __restrict__ f4,
    const float* __restrict__ f5, const float* __restrict__ f6,
    __hip_bfloat16* __restrict__ ws)
{
    __shared__ float tile[64][65];
    const int z   = blockIdx.z;         // lvl*4 + b
    const int lvl = z >> 2;
    const int b   = z & 3;
    const float* in; int H; size_t base;
    if      (lvl == 0) { in = f3; H = 128; base = B3; }
    else if (lvl == 1) { in = f4; H = 64;  base = B4; }
    else if (lvl == 2) { in = f5; H = 32;  base = B5; }
    else               { in = f6; H = 16;  base = B6; }
    const int HW  = H * H;
    const int hw0 = blockIdx.x * 64;
    if (hw0 >= HW) return;
    const int c0  = blockIdx.y * 64;
    const int tx  = threadIdx.x & 63;
    const int ty  = threadIdx.x >> 6;

    const float* inp = in + ((size_t)b * 256 + c0) * (size_t)HW + hw0;
    #pragma unroll
    for (int i = 0; i < 16; ++i) {
        const int cl = ty + 4 * i;
        tile[cl][tx] = inp[(size_t)cl * HW + tx];          // 256B/wave coalesced
    }
    __syncthreads();
    __hip_bfloat16* outp = ws + base + ((size_t)b * HW + hw0) * 256 + c0;
    #pragma unroll
    for (int i = 0; i < 16; ++i) {
        const int hl = ty + 4 * i;
        outp[(size_t)hl * 256 + tx] = __float2bfloat16(tile[tx][hl]);  // 128B/wave, full line
    }
}

// ---------------- ROI gather from bf16 NHWC --------------------------------
__device__ __forceinline__ float bf_lo(unsigned u) { return __uint_as_float(u << 16); }
__device__ __forceinline__ float bf_hi(unsigned u) { return __uint_as_float(u & 0xffff0000u); }

__global__ __launch_bounds__(256) void roi_gather_nhwc_bf16(
    const unsigned* __restrict__ ws, const float* __restrict__ boxes,
    const int* __restrict__ img_ids, float* __restrict__ out)
{
    __shared__ float lds[49][129];      // [bin][channel] staging
    __shared__ float rW[14][2];         // {hy, ly}  (zeroed if row-invalid)
    __shared__ int   rO[14][2];         // {yl, yh} * H * 128   (uint offsets)
    __shared__ float cW[14][2];         // {hx, lx}  (zeroed if col-invalid)
    __shared__ int   cO[14][2];         // {xl, xh} * 128

    const int n    = blockIdx.x;        // ROI
    const int c0   = blockIdx.y * 128;  // channel half
    const int t    = threadIdx.x;
    const int lane = t & 63;
    const int wv   = t >> 6;            // 0..3

    const float by = boxes[n * 4 + 0];
    const float bx = boxes[n * 4 + 1];
    const float bh = boxes[n * 4 + 2];
    const float bw = boxes[n * 4 + 3];

    float kf = floorf(4.0f + log2f(sqrtf(bh * bw) / 224.0f));
    kf = fminf(fmaxf(kf, 3.0f), 6.0f);
    const int lvl = (int)kf;

    int H; size_t base;
    if      (lvl == 3) { H = 128; base = B3; }
    else if (lvl == 4) { H = 64;  base = B4; }
    else if (lvl == 5) { H = 32;  base = B5; }
    else               { H = 16;  base = B6; }
    const float inv_stride = 1.0f / (float)(1 << lvl);
    const float Hf = (float)H;

    // tlbr/stride with the reference's swapped axis semantics (round-1/2 verified)
    const float tY = (by - bh * 0.5f) * inv_stride;
    const float lX = (bx - bw * 0.5f) * inv_stride;
    const float bY = (by + bh * 0.5f) * inv_stride;
    const float rX = (bx + bw * 0.5f) * inv_stride;
    const float binA = fmaxf(bY - tY, 1.0f) * (1.0f / 7.0f);  // col direction
    const float binB = fmaxf(rX - lX, 1.0f) * (1.0f / 7.0f);  // row direction

    // separable sampling tables: 14 row coords, 14 col coords
    if (lane < 14 && wv < 2) {
        const int a = lane;
        const float off = (float)(a >> 1) + 0.25f + 0.5f * (float)(a & 1);
        if (wv == 0) {
            const float rc = lX + off * binB;
            const bool v = (rc >= -1.0f) && (rc <= Hf);
            const float yc = fminf(fmaxf(rc, 0.0f), Hf - 1.0f);
            const int yl = (int)yc;
            const int yh = min(yl + 1, H - 1);
            const float ly = yc - (float)yl;
            rW[a][0] = v ? 1.0f - ly : 0.0f;
            rW[a][1] = v ? ly : 0.0f;
            rO[a][0] = yl * H * 128;
            rO[a][1] = yh * H * 128;
        } else {
            const float cc = tY + off * binA;
            const bool v = (cc >= -1.0f) && (cc <= Hf);
            const float xc = fminf(fmaxf(cc, 0.0f), Hf - 1.0f);
            const int xl = (int)xc;
            const int xh = min(xl + 1, H - 1);
            const float lx = xc - (float)xl;
            cW[a][0] = v ? 1.0f - lx : 0.0f;
            cW[a][1] = v ? lx : 0.0f;
            cO[a][0] = xl * 128;
            cO[a][1] = xh * 128;
        }
    }
    __syncthreads();

    const int img = img_ids[n];
    const unsigned* fb = ws + (base >> 1) + (size_t)img * (size_t)(H * H) * 128
                       + (size_t)(c0 >> 1) + lane;

    for (int p = wv; p < 49; p += 4) {
        const int a0 = (p / 7) * 2;
        const int b0 = (p % 7) * 2;
        float accx = 0.0f, accy = 0.0f;
        #pragma unroll
        for (int s1 = 0; s1 < 2; ++s1) {
            const float hy = rW[a0 + s1][0], lyw = rW[a0 + s1][1];
            const int oy0 = rO[a0 + s1][0], oy1 = rO[a0 + s1][1];
            #pragma unroll
            for (int s2 = 0; s2 < 2; ++s2) {
                const float hx = cW[b0 + s2][0], lxw = cW[b0 + s2][1];
                const int ox0 = cO[b0 + s2][0], ox1 = cO[b0 + s2][1];
                const unsigned u00 = fb[oy0 + ox0];
                const unsigned u01 = fb[oy0 + ox1];
                const unsigned u10 = fb[oy1 + ox0];
                const unsigned u11 = fb[oy1 + ox1];
                const float w00 = hy * hx, w01 = hy * lxw;
                const float w10 = lyw * hx, w11 = lyw * lxw;
                accx += w00 * bf_lo(u00) + w01 * bf_lo(u01)
                      + w10 * bf_lo(u10) + w11 * bf_lo(u11);
                accy += w00 * bf_hi(u00) + w01 * bf_hi(u01)
                      + w10 * bf_hi(u10) + w11 * bf_hi(u11);
            }
        }
        lds[p][2 * lane]     = accx * 0.25f;
        lds[p][2 * lane + 1] = accy * 0.25f;
    }
    __syncthreads();

    // coalesced NCHW write-out: lanes = bins, loop channels
    float* op = out + ((size_t)n * 256 + c0 + wv * 32) * 49;
    if (lane < 49) {
        for (int k = 0; k < 32; ++k) {
            op[(size_t)k * 49 + lane] = lds[lane][wv * 32 + k];
        }
    }
}

// ---------------- fallback (round-1, direct NCHW gather) -------------------
__global__ __launch_bounds__(256) void roi_align_fallback(
    const float* __restrict__ f3, const float* __restrict__ f4,
    const float* __restrict__ f5, const float* __restrict__ f6,
    const float* __restrict__ boxes, const int* __restrict__ img_ids,
    float* __restrict__ out)
{
    const int n  = blockIdx.x;
    const int cg = blockIdx.y;
    const int t  = threadIdx.x;

    const float by = boxes[n * 4 + 0];
    const float bx = boxes[n * 4 + 1];
    const float bh = boxes[n * 4 + 2];
    const float bw = boxes[n * 4 + 3];

    float kf = floorf(4.0f + log2f(sqrtf(bh * bw) / 224.0f));
    kf = fminf(fmaxf(kf, 3.0f), 6.0f);
    const int lvl = (int)kf;

    const float* feat;
    int H;
    if      (lvl == 3) { feat = f3; H = 128; }
    else if (lvl == 4) { feat = f4; H = 64;  }
    else if (lvl == 5) { feat = f5; H = 32;  }
    else               { feat = f6; H = 16;  }

    const float inv_stride = 1.0f / (float)(1 << lvl);
    const float tY = (by - bh * 0.5f) * inv_stride;
    const float lX = (bx - bw * 0.5f) * inv_stride;
    const float bY = (by + bh * 0.5f) * inv_stride;
    const float rX = (bx + bw * 0.5f) * inv_stride;
    const float binA = fmaxf(bY - tY, 1.0f) / 7.0f;
    const float binB = fmaxf(rX - lX, 1.0f) / 7.0f;

    const int p   = t >> 2;
    const int s1  = (t >> 1) & 1;
    const int s2  = t & 1;
    const int ii  = p / 7;
    const int jj  = p % 7;
    const bool active = (t < 196);

    const float rc = lX + ((float)ii + ((float)s1 + 0.5f) * 0.5f) * binB;
    const float cc = tY + ((float)jj + ((float)s2 + 0.5f) * 0.5f) * binA;
    const float Hf = (float)H;
    const bool valid = active && (rc >= -1.0f) && (rc <= Hf) &&
                       (cc >= -1.0f) && (cc <= Hf);

    const float yc = fminf(fmaxf(rc, 0.0f), Hf - 1.0f);
    const float xc = fminf(fmaxf(cc, 0.0f), Hf - 1.0f);
    int yl = (int)floorf(yc);
    int xl = (int)floorf(xc);
    int yh = min(yl + 1, H - 1);
    int xh = min(xl + 1, H - 1);
    const float ly = yc - (float)yl;
    const float lx = xc - (float)xl;
    const float hy = 1.0f - ly;
    const float hx = 1.0f - lx;
    float w00 = hy * hx, w01 = hy * lx, w10 = ly * hx, w11 = ly * lx;
    if (!valid) { w00 = w01 = w10 = w11 = 0.0f; yl = xl = yh = xh = 0; }

    const int img = img_ids[n];
    const int HH  = H * H;
    const int c0  = cg * 64;
    const float* basep = feat + (size_t)(img * 256 + c0) * (size_t)HH;
    const int o00 = yl * H + xl, o01 = yl * H + xh;
    const int o10 = yh * H + xl, o11 = yh * H + xh;

    float* outp = out + ((size_t)n * 256 + c0) * 49 + p;
    #pragma unroll 4
    for (int c = 0; c < 64; ++c) {
        float v = w00 * basep[o00] + w01 * basep[o01]
                + w10 * basep[o10] + w11 * basep[o11];
        v += __shfl_xor(v, 1);
        v += __shfl_xor(v, 2);
        if (active && (t & 3) == 0) outp[(size_t)c * 49] = v * 0.25f;
        basep += HH;
    }
}

extern "C" void kernel_launch(void* const* d_in, const int* in_sizes, int n_in,
                              void* d_out, int out_size, void* d_ws, size_t ws_size,
                              hipStream_t stream)
{
    const float* f3      = (const float*)d_in[0];
    const float* f4      = (const float*)d_in[1];
    const float* f5      = (const float*)d_in[2];
    const float* f6      = (const float*)d_in[3];
    const float* boxes   = (const float*)d_in[4];
    const int*   img_ids = (const int*)d_in[5];
    float* outp          = (float*)d_out;
    const int N = in_sizes[5];                    // 1024 ROIs

    if (ws_size >= WS_ELEMS * sizeof(__hip_bfloat16)) {
        __hip_bfloat16* ws = (__hip_bfloat16*)d_ws;
        dim3 tgrid(256, 4, 16);                   // (hw tiles max, c tiles, lvl*4+b)
        transpose_nchw_nhwc_bf16<<<tgrid, 256, 0, stream>>>(f3, f4, f5, f6, ws);
        dim3 ggrid(N, 2);                         // (roi, channel half)
        roi_gather_nhwc_bf16<<<ggrid, 256, 0, stream>>>((const unsigned*)d_ws, boxes, img_ids, outp);
    } else {
        dim3 grid(N, 4);
        roi_align_fallback<<<grid, 256, 0, stream>>>(f3, f4, f5, f6, boxes, img_ids, outp);
    }
}